// Round 9
// baseline (94.075 us; speedup 1.0000x reference)
//
#include <hip/hip_runtime.h>
#include <hip/hip_fp16.h>
#include <hip/hip_cooperative_groups.h>

#define NN 1024
#define HID 256
#define XD 128

typedef _Float16 h2 __attribute__((ext_vector_type(2)));
typedef _Float16 h8 __attribute__((ext_vector_type(8)));

// wsh (halves):
//   px [0, 262144)  tiled: idx = ((jt*8+kg)*8 + ks*2+jj)*512 + ln*8 + kl
//       jt=j>>7, jj=(j>>6)&1, ln=j&63; kg=k>>5, ks=(k>>3)&3, kl=k&7
//   py [262144, 524288)  row-major [i][k]  (b1 folded in)
//   w2h [524288, 524544)
// wsf (floats) at byte 1049600:
#define WSF_BYTE_OFF 1049600
#define F_C     0        // 1024 : c[j] = exp(b2 - ls[j])
#define F_T0P   1024     // 256
#define F_LSP   1280     // 256
#define F_PART  1536     // 256 : per-block exp-sum partials

__device__ __forceinline__ h2 relu2(h2 x) {
  h2 z = {(_Float16)0, (_Float16)0};
  return __builtin_elementwise_max(x, z);
}

__device__ __forceinline__ float dot2f(h2 a, h2 b, float c) {
  return __builtin_amdgcn_fdot2(a, b, c, false);
}

__global__ __launch_bounds__(512) void fused_kernel(
    const float* __restrict__ x, const float* __restrict__ y,
    const float* __restrict__ W1, const float* __restrict__ b1,
    const float* __restrict__ w2, const float* __restrict__ b2p,
    const float* __restrict__ wb, const float* __restrict__ bbp,
    _Float16* __restrict__ wsh, float* __restrict__ wsf,
    float* __restrict__ out)
{
  __shared__ __align__(16) char smem[41024];
  const int t = threadIdx.x;
  const int blk = blockIdx.x;

  // ================= Phase A: prep (4 rows per block) =================
  {
    float* sx   = (float*)smem;          // [4][128]
    float* sy   = sx + 512;              // [4][128]
    float* spy2 = sy + 512;              // [4][256]
    float* st0  = spy2 + 1024;           // [4][4]
    float* sls  = st0 + 16;              // [4]
    const int r0 = blk * 4;

    if (t < 128) {
      const int rl = t >> 5, f = t & 31;
      *(float4*)(sx + rl * 128 + f * 4) = *(const float4*)(x + (r0 + rl) * XD + f * 4);
    } else if (t < 256) {
      const int t2 = t - 128, rl = t2 >> 5, f = t2 & 31;
      *(float4*)(sy + rl * 128 + f * 4) = *(const float4*)(y + (r0 + rl) * XD + f * 4);
    }
    __syncthreads();

    const int side = t >> 8;  // 0: px, 1: py
    const int k = t & 255;
    float ap[4] = {0.f, 0.f, 0.f, 0.f};
    const float* wrow = W1 + k * 256 + side * 128;
    const float* sm0 = side ? sy : sx;
#pragma unroll 8
    for (int dq = 0; dq < 32; ++dq) {
      float4 wv = *(const float4*)(wrow + dq * 4);
#pragma unroll
      for (int r = 0; r < 4; ++r) {
        float4 sv = *(const float4*)(sm0 + r * 128 + dq * 4);
        ap[r] = fmaf(sv.x, wv.x, ap[r]);
        ap[r] = fmaf(sv.y, wv.y, ap[r]);
        ap[r] = fmaf(sv.z, wv.z, ap[r]);
        ap[r] = fmaf(sv.w, wv.w, ap[r]);
      }
    }

    if (side == 1) {
      const float b1k = b1[k];
#pragma unroll
      for (int r = 0; r < 4; ++r) {
        ap[r] += b1k;
        spy2[r * 256 + k] = ap[r];
        wsh[262144 + (r0 + r) * 256 + k] = (_Float16)ap[r];
      }
    } else {
      const int kg = k >> 5, ks = (k >> 3) & 3, kl = k & 7;
#pragma unroll
      for (int r = 0; r < 4; ++r) {
        const int j = r0 + r;
        const int jt = j >> 7, jj = (j >> 6) & 1, ln = j & 63;
        wsh[((jt * 8 + kg) * 8 + ks * 2 + jj) * 512 + ln * 8 + kl] = (_Float16)ap[r];
      }
    }
    __syncthreads();

    if (side == 0) {
      const float w2k = w2[k];
      const int wv = t >> 6, lane = t & 63;
#pragma unroll
      for (int r = 0; r < 4; ++r) {
        float v = fmaxf(ap[r] + spy2[r * 256 + k], 0.f) * w2k;
        for (int o = 32; o > 0; o >>= 1) v += __shfl_down(v, o);
        if (lane == 0) st0[wv * 4 + r] = v;
      }
    } else if ((t & 255) < 128) {
      const int t2 = t & 255, rl = t2 >> 5, f = t2 & 31;
      float p = 0.f;
#pragma unroll
      for (int l = 0; l < 4; ++l) p = fmaf(sy[rl * 128 + f * 4 + l], wb[f * 4 + l], p);
      for (int m = 16; m > 0; m >>= 1) p += __shfl_xor(p, m);
      if (f == 0) {
        const float lsv = p + bbp[0];
        sls[rl] = lsv;
        wsf[F_C + r0 + rl] = __expf(b2p[0] - lsv);
      }
    }
    __syncthreads();

    if (t == 0) {
      const float b2v = b2p[0];
      float t0s = 0.f, lss = 0.f;
#pragma unroll
      for (int r = 0; r < 4; ++r) {
        t0s += st0[r] + st0[4 + r] + st0[8 + r] + st0[12 + r] + b2v;
        lss += sls[r];
      }
      wsf[F_T0P + blk] = t0s;
      wsf[F_LSP + blk] = lss;
    }
    if (blk == 0 && t < 128) {
      h2 wv2;
      wv2.x = (_Float16)w2[2 * t];
      wv2.y = (_Float16)w2[2 * t + 1];
      ((h2*)(wsh + 524288))[t] = wv2;
    }
  }

  cooperative_groups::this_grid().sync();

  // ================= Phase B: pairwise main =================
  // blk -> bj = blk&7 (j-tile 128), ig = blk>>3 (i-range 32, two 16-i iters)
  {
    _Float16* spy  = (_Float16*)smem;       // [16][256]  (8 KB)
    float*    sCmb = (float*)(smem + 8192); // [4][16][128] (32 KB)
    const int lane = t & 63;
    const int kg = t >> 6;                  // 0..7 (32 k each)
    const int bj = blk & 7;
    const int ig = blk >> 3;

    h8 pxr[8];
    {
      const float4* gpx = (const float4*)wsh + ((bj * 8 + kg) * 8) * 64 + lane;
#pragma unroll
      for (int q = 0; q < 8; ++q) ((float4*)pxr)[q] = gpx[q * 64];
    }
    h8 w2r[4];
    {
      const float4* gw2 = (const float4*)(wsh + 524288);
#pragma unroll
      for (int qq = 0; qq < 4; ++qq) ((float4*)w2r)[qq] = gw2[kg * 4 + qq];
    }
    const float cj0 = wsf[F_C + bj * 128 + lane];
    const float cj1 = wsf[F_C + bj * 128 + 64 + lane];

    float part = 0.f;
#pragma unroll 1
    for (int it = 0; it < 2; ++it) {
      const int i0 = ig * 32 + it * 16;
      __syncthreads();
      ((float4*)spy)[t] = ((const float4*)(wsh + 262144))[i0 * 32 + t];
      __syncthreads();

      float acc[16][2];
#pragma unroll
      for (int ii = 0; ii < 16; ++ii) { acc[ii][0] = 0.f; acc[ii][1] = 0.f; }

#pragma unroll
      for (int ii = 0; ii < 16; ++ii) {
        const h8* pf = (const h8*)(spy + ii * 256 + kg * 32);
        h8 p0 = pf[0], p1 = pf[1], p2 = pf[2], p3 = pf[3];
#pragma unroll
        for (int jj = 0; jj < 2; ++jj) {
          float s = acc[ii][jj];
          {
            const h2* pk = (const h2*)&p0; const h2* wk = (const h2*)&w2r[0];
            const h2* xk = (const h2*)&pxr[jj];
            s = dot2f(relu2(xk[0] + pk[0]), wk[0], s);
            s = dot2f(relu2(xk[1] + pk[1]), wk[1], s);
            s = dot2f(relu2(xk[2] + pk[2]), wk[2], s);
            s = dot2f(relu2(xk[3] + pk[3]), wk[3], s);
          }
          {
            const h2* pk = (const h2*)&p1; const h2* wk = (const h2*)&w2r[1];
            const h2* xk = (const h2*)&pxr[2 + jj];
            s = dot2f(relu2(xk[0] + pk[0]), wk[0], s);
            s = dot2f(relu2(xk[1] + pk[1]), wk[1], s);
            s = dot2f(relu2(xk[2] + pk[2]), wk[2], s);
            s = dot2f(relu2(xk[3] + pk[3]), wk[3], s);
          }
          {
            const h2* pk = (const h2*)&p2; const h2* wk = (const h2*)&w2r[2];
            const h2* xk = (const h2*)&pxr[4 + jj];
            s = dot2f(relu2(xk[0] + pk[0]), wk[0], s);
            s = dot2f(relu2(xk[1] + pk[1]), wk[1], s);
            s = dot2f(relu2(xk[2] + pk[2]), wk[2], s);
            s = dot2f(relu2(xk[3] + pk[3]), wk[3], s);
          }
          {
            const h2* pk = (const h2*)&p3; const h2* wk = (const h2*)&w2r[3];
            const h2* xk = (const h2*)&pxr[6 + jj];
            s = dot2f(relu2(xk[0] + pk[0]), wk[0], s);
            s = dot2f(relu2(xk[1] + pk[1]), wk[1], s);
            s = dot2f(relu2(xk[2] + pk[2]), wk[2], s);
            s = dot2f(relu2(xk[3] + pk[3]), wk[3], s);
          }
          acc[ii][jj] = s;
        }
      }

      // 3-round tree combine over kg
      if (kg >= 4) {
#pragma unroll
        for (int ii = 0; ii < 16; ++ii) {
          sCmb[((kg - 4) * 16 + ii) * 128 + lane]      = acc[ii][0];
          sCmb[((kg - 4) * 16 + ii) * 128 + 64 + lane] = acc[ii][1];
        }
      }
      __syncthreads();
      if (kg < 4) {
#pragma unroll
        for (int ii = 0; ii < 16; ++ii) {
          acc[ii][0] += sCmb[(kg * 16 + ii) * 128 + lane];
          acc[ii][1] += sCmb[(kg * 16 + ii) * 128 + 64 + lane];
        }
      }
      __syncthreads();
      if (kg == 2 || kg == 3) {
#pragma unroll
        for (int ii = 0; ii < 16; ++ii) {
          sCmb[((kg - 2) * 16 + ii) * 128 + lane]      = acc[ii][0];
          sCmb[((kg - 2) * 16 + ii) * 128 + 64 + lane] = acc[ii][1];
        }
      }
      __syncthreads();
      if (kg < 2) {
#pragma unroll
        for (int ii = 0; ii < 16; ++ii) {
          acc[ii][0] += sCmb[(kg * 16 + ii) * 128 + lane];
          acc[ii][1] += sCmb[(kg * 16 + ii) * 128 + 64 + lane];
        }
      }
      __syncthreads();
      if (kg == 1) {
#pragma unroll
        for (int ii = 0; ii < 16; ++ii) {
          sCmb[ii * 128 + lane]      = acc[ii][0];
          sCmb[ii * 128 + 64 + lane] = acc[ii][1];
        }
      }
      __syncthreads();
      if (kg == 0) {
#pragma unroll
        for (int ii = 0; ii < 16; ++ii) {
          part += __expf(acc[ii][0] + sCmb[ii * 128 + lane]) * cj0;
          part += __expf(acc[ii][1] + sCmb[ii * 128 + 64 + lane]) * cj1;
        }
      }
    }
    if (kg == 0) {
      for (int o = 32; o > 0; o >>= 1) part += __shfl_down(part, o);
      if (lane == 0) wsf[F_PART + blk] = part;
    }
  }

  cooperative_groups::this_grid().sync();

  // ================= Phase C: finalize (block 0) =================
  if (blk == 0) {
    float* sr = (float*)smem;  // [8][3]
    float e = 0.f, t0v = 0.f, lsv = 0.f;
    if (t < 256) {
      e   = wsf[F_PART + t];
      t0v = wsf[F_T0P + t];
      lsv = wsf[F_LSP + t];
    }
    for (int o = 32; o > 0; o >>= 1) {
      e   += __shfl_down(e, o);
      t0v += __shfl_down(t0v, o);
      lsv += __shfl_down(lsv, o);
    }
    __syncthreads();
    if ((t & 63) == 0) {
      sr[(t >> 6) * 3 + 0] = e;
      sr[(t >> 6) * 3 + 1] = t0v;
      sr[(t >> 6) * 3 + 2] = lsv;
    }
    __syncthreads();
    if (t == 0) {
      float es = 0.f, t0s = 0.f, lss = 0.f;
#pragma unroll
      for (int w = 0; w < 8; ++w) {
        es  += sr[w * 3 + 0];
        t0s += sr[w * 3 + 1];
        lss += sr[w * 3 + 2];
      }
      out[0] = 1.0f + t0s * (1.0f / 1024.0f) - lss * (1.0f / 1024.0f)
                    - es * (1.0f / 1048576.0f);
    }
  }
}

extern "C" void kernel_launch(void* const* d_in, const int* in_sizes, int n_in,
                              void* d_out, int out_size, void* d_ws, size_t ws_size,
                              hipStream_t stream) {
  const float* x  = (const float*)d_in[0];
  const float* y  = (const float*)d_in[1];
  const float* W1 = (const float*)d_in[2];
  const float* b1 = (const float*)d_in[3];
  const float* w2 = (const float*)d_in[4];
  const float* b2 = (const float*)d_in[5];
  const float* wb = (const float*)d_in[6];
  const float* bb = (const float*)d_in[7];
  _Float16* wsh = (_Float16*)d_ws;
  float* wsf = (float*)((char*)d_ws + WSF_BYTE_OFF);
  float* out = (float*)d_out;

  void* kargs[] = {(void*)&x, (void*)&y, (void*)&W1, (void*)&b1,
                   (void*)&w2, (void*)&b2, (void*)&wb, (void*)&bb,
                   (void*)&wsh, (void*)&wsf, (void*)&out};
  hipLaunchCooperativeKernel((void*)fused_kernel, dim3(256), dim3(512),
                             kargs, 0, stream);
}

// Round 10
// 39.774 us; speedup vs baseline: 2.3652x; 2.3652x over previous
//
#include <hip/hip_runtime.h>
#include <hip/hip_fp16.h>

#define NN 1024
#define HID 256
#define XD 128

typedef _Float16 h2 __attribute__((ext_vector_type(2)));

// wsh (halves):
//   pxt [0, 262144)   tiled [jblk16][ko32][slot64][kl8]
//   pyt [262144, 524288)  same tiling over i (b1 folded in)
//   w2h [524288, 524544)
// wsf (floats) at byte 1049600:
#define WSF_BYTE_OFF 1049600
#define F_C    0      // 1024 : c[j] = exp(b2 - ls[j])
#define F_PART 1024   // 256  : per-main-block exp-sum partials
#define F_T0P  3072   // 256  : per-prep-block T0 partials
#define F_LSP  3328   // 256  : per-prep-block ls partials
#define F_CNT  3584   // 1 uint: completed-block counter

__device__ __forceinline__ h2 relu2(h2 x) {
  h2 z = {(_Float16)0, (_Float16)0};
  return __builtin_elementwise_max(x, z);
}

__device__ __forceinline__ float dot2f(h2 a, h2 b, float c) {
  return __builtin_amdgcn_fdot2(a, b, c, false);
}

__global__ __launch_bounds__(256) void prep_kernel(
    const float* __restrict__ x, const float* __restrict__ y,
    const float* __restrict__ W1, const float* __restrict__ b1,
    const float* __restrict__ w2, const float* __restrict__ b2p,
    const float* __restrict__ wb, const float* __restrict__ bbp,
    _Float16* __restrict__ wsh, float* __restrict__ wsf)
{
  __shared__ float sx[4][128];
  __shared__ float sy[4][128];
  __shared__ float st0[4][4];
  __shared__ float sls[4];
  const int t = threadIdx.x;
  const int blk = blockIdx.x;
  const int r0 = blk * 4;

  {
    const int rl = (t & 127) >> 5, f = t & 31;
    if (t < 128) {
      *(float4*)&sx[rl][f * 4] = *(const float4*)(x + (r0 + rl) * XD + f * 4);
    } else {
      *(float4*)&sy[rl][f * 4] = *(const float4*)(y + (r0 + rl) * XD + f * 4);
    }
  }
  __syncthreads();

  const int k = t;  // one hidden unit per thread
  float apx[4] = {0,0,0,0};
  float apy[4] = {0,0,0,0};
  const float* wrow = W1 + k * 256;
  for (int dq = 0; dq < 32; ++dq) {
    float4 wx = *(const float4*)(wrow + dq * 4);
    float4 wy = *(const float4*)(wrow + 128 + dq * 4);
#pragma unroll
    for (int r = 0; r < 4; ++r) {
      float4 xv = *(const float4*)&sx[r][dq * 4];
      float4 yv = *(const float4*)&sy[r][dq * 4];
      apx[r] = fmaf(xv.x, wx.x, apx[r]);
      apx[r] = fmaf(xv.y, wx.y, apx[r]);
      apx[r] = fmaf(xv.z, wx.z, apx[r]);
      apx[r] = fmaf(xv.w, wx.w, apx[r]);
      apy[r] = fmaf(yv.x, wy.x, apy[r]);
      apy[r] = fmaf(yv.y, wy.y, apy[r]);
      apy[r] = fmaf(yv.z, wy.z, apy[r]);
      apy[r] = fmaf(yv.w, wy.w, apy[r]);
    }
  }
  const float b1k = b1[k];
#pragma unroll
  for (int r = 0; r < 4; ++r) apy[r] += b1k;  // fold b1 into py

  // write f16 tiled layouts
  {
    const int ko = k >> 3, kl = k & 7;
    _Float16* pxh = wsh;
    _Float16* pyh = wsh + 262144;
#pragma unroll
    for (int r = 0; r < 4; ++r) {
      const int j = r0 + r;
      const int idx = (j >> 6) * 16384 + ko * 512 + (j & 63) * 8 + kl;
      pxh[idx] = (_Float16)apx[r];
      pyh[idx] = (_Float16)apy[r];
    }
  }

  // T0 partials (exact f32)
  const float w2k = w2[k];
  const float b2v = b2p[0];
  const int wv = t >> 6, lane = t & 63;
#pragma unroll
  for (int r = 0; r < 4; ++r) {
    float v = fmaxf(apx[r] + apy[r], 0.f) * w2k;
    for (int o = 32; o > 0; o >>= 1) v += __shfl_down(v, o);
    if (lane == 0) st0[wv][r] = v;
  }

  // ls[r] = y[r].wb + bb ; c[r] = exp(b2 - ls[r])
  if (t < 128) {
    const int rl = t >> 5, f = t & 31;
    float p = 0.f;
#pragma unroll
    for (int l = 0; l < 4; ++l) p = fmaf(sy[rl][f * 4 + l], wb[f * 4 + l], p);
    for (int m = 16; m > 0; m >>= 1) p += __shfl_xor(p, m);
    if (f == 0) {
      const float lsv = p + bbp[0];
      sls[rl] = lsv;
      wsf[F_C + r0 + rl] = __expf(b2v - lsv);
    }
  }
  __syncthreads();
  if (t == 0) {
    float t0s = 0.f, lss = 0.f;
#pragma unroll
    for (int r = 0; r < 4; ++r) {
      t0s += st0[0][r] + st0[1][r] + st0[2][r] + st0[3][r] + b2v;
      lss += sls[r];
    }
    wsf[F_T0P + blk] = t0s;
    wsf[F_LSP + blk] = lss;
  }
  if (blk == 0) {
    if (t == 0) *((unsigned*)(wsf + F_CNT)) = 0u;  // reset finalize counter
    if (t < 128) {
      h2 wv2;
      wv2.x = (_Float16)w2[2 * t];
      wv2.y = (_Float16)w2[2 * t + 1];
      ((h2*)(wsh + 524288))[t] = wv2;
    }
  }
}

__global__ __launch_bounds__(512) void main_kernel(
    const _Float16* __restrict__ wsh, float* __restrict__ wsf,
    float* __restrict__ out)
{
  __shared__ _Float16 spx[16384];  // [ko32][slot64][kl8] = 32KB
  __shared__ _Float16 spy[16384];
  __shared__ float sred[8];
  __shared__ unsigned sdone;
  const int t = threadIdx.x;
  const int lane = t & 63;
  const int w = t >> 6;
  const int tx = t & 15;        // j col group: cols u*16+tx
  const int ty = t >> 4;        // 0..31, i rows v*32+ty
  const int blk = blockIdx.x;
  const int bi = blk >> 4, bj = blk & 15;

  const float4* gx = (const float4*)(wsh + bj * 16384);
  const float4* gy = (const float4*)(wsh + 262144 + bi * 16384);
  const float4* gw = (const float4*)(wsh + 524288);
  float4* lx = (float4*)spx;
  float4* ly = (float4*)spy;
#pragma unroll
  for (int it = 0; it < 4; ++it) {
    lx[it * 512 + t] = gx[it * 512 + t];
    ly[it * 512 + t] = gy[it * 512 + t];
  }
  __syncthreads();

  float acc[2][4] = {{0.f,0.f,0.f,0.f},{0.f,0.f,0.f,0.f}};
  const float4* spx4 = (const float4*)spx;
  const float4* spy4 = (const float4*)spy;

#pragma unroll 2
  for (int ko = 0; ko < 32; ++ko) {
    float4 wv = gw[ko];                  // uniform, L1-cached
    float4 Af[4], Bf[2];
#pragma unroll
    for (int u = 0; u < 4; ++u) Af[u] = spx4[ko * 64 + u * 16 + tx];
#pragma unroll
    for (int v = 0; v < 2; ++v) Bf[v] = spy4[ko * 64 + v * 32 + ty];
    const h2* wq = (const h2*)&wv;
#pragma unroll
    for (int v = 0; v < 2; ++v) {
      const h2* bh = (const h2*)&Bf[v];
#pragma unroll
      for (int u = 0; u < 4; ++u) {
        const h2* ah = (const h2*)&Af[u];
        float s = acc[v][u];
#pragma unroll
        for (int p = 0; p < 4; ++p) {
          h2 uu = ah[p] + bh[p];         // v_pk_add_f16
          uu = relu2(uu);                // v_pk_max_f16
          s = dot2f(uu, wq[p], s);       // v_dot2_f32_f16
        }
        acc[v][u] = s;
      }
    }
  }

  // epilogue: per-block partial of sum exp(S)*c[j]
  const float* cj = wsf + F_C + bj * 64;
  const float c0 = cj[tx], c1 = cj[16 + tx], c2 = cj[32 + tx], c3 = cj[48 + tx];
  float ts = 0.f;
#pragma unroll
  for (int v = 0; v < 2; ++v) {
    ts += __expf(acc[v][0]) * c0;
    ts += __expf(acc[v][1]) * c1;
    ts += __expf(acc[v][2]) * c2;
    ts += __expf(acc[v][3]) * c3;
  }
  for (int o = 32; o > 0; o >>= 1) ts += __shfl_down(ts, o);
  if (lane == 0) sred[w] = ts;
  __syncthreads();
  if (t == 0) {
    float bs = ((sred[0] + sred[1]) + (sred[2] + sred[3]))
             + ((sred[4] + sred[5]) + (sred[6] + sred[7]));
    wsf[F_PART + blk] = bs;
    __threadfence();                     // release partial at device scope
    unsigned old = atomicAdd((unsigned*)(wsf + F_CNT), 1u);
    sdone = (old == 255u) ? 1u : 0u;
  }
  __syncthreads();

  // last finished block does the finalize (deterministic fixed-order sums)
  if (sdone) {
    __threadfence();                     // acquire
    float e = 0.f, t0v = 0.f, lsv = 0.f;
    if (t < 256) {
      e = __hip_atomic_load(wsf + F_PART + t, __ATOMIC_ACQUIRE,
                            __HIP_MEMORY_SCOPE_AGENT);
      t0v = wsf[F_T0P + t];
      lsv = wsf[F_LSP + t];
    }
    for (int o = 32; o > 0; o >>= 1) {
      e   += __shfl_down(e, o);
      t0v += __shfl_down(t0v, o);
      lsv += __shfl_down(lsv, o);
    }
    __syncthreads();  // sred reuse
    if (lane == 0) {
      sred[w] = e;
      ((float*)sred)[w] = e;  // waves 4-7 hold zeros
    }
    __shared__ float sfin[8][2];
    if (lane == 0) { sfin[w][0] = t0v; sfin[w][1] = lsv; }
    __syncthreads();
    if (t == 0) {
      float es = 0.f, t0s = 0.f, lss = 0.f;
#pragma unroll
      for (int q = 0; q < 8; ++q) {
        es  += sred[q];
        t0s += sfin[q][0];
        lss += sfin[q][1];
      }
      out[0] = 1.0f + t0s * (1.0f / 1024.0f) - lss * (1.0f / 1024.0f)
                    - es * (1.0f / 1048576.0f);
    }
  }
}

extern "C" void kernel_launch(void* const* d_in, const int* in_sizes, int n_in,
                              void* d_out, int out_size, void* d_ws, size_t ws_size,
                              hipStream_t stream) {
  const float* x  = (const float*)d_in[0];
  const float* y  = (const float*)d_in[1];
  const float* W1 = (const float*)d_in[2];
  const float* b1 = (const float*)d_in[3];
  const float* w2 = (const float*)d_in[4];
  const float* b2 = (const float*)d_in[5];
  const float* wb = (const float*)d_in[6];
  const float* bb = (const float*)d_in[7];
  _Float16* wsh = (_Float16*)d_ws;
  float* wsf = (float*)((char*)d_ws + WSF_BYTE_OFF);
  float* out = (float*)d_out;

  hipLaunchKernelGGL(prep_kernel, dim3(256), dim3(256), 0, stream,
                     x, y, W1, b1, w2, b2, wb, bb, wsh, wsf);
  hipLaunchKernelGGL(main_kernel, dim3(256), dim3(512), 0, stream,
                     wsh, wsf, out);
}